// Round 10
// baseline (110.086 us; speedup 1.0000x reference)
//
#include <hip/hip_runtime.h>

// ---------------------------------------------------------------------------
// PYG_GCN: y = relu(x@W_in+b_in) -> GCNConv(W_gcn,b_gcn) -> relu -> @W_cls+b_cls
// N=50000, E=600000, D=128, C=40.
// R10: 4 launches. CSR never materialized: per-bucket fine sort done in LDS
// inside the fused agg+out kernel. deg via global int-hist hidden under GEMM1;
// dinv folded into GEMM2 epilogue (single rounding).
//   L1 prep||chist||zero-deg -> L2 scan||deg-hist||GEMM1
//   -> L3 reorder||GEMM2(scaled) -> L4 sort+agg+out
// ---------------------------------------------------------------------------

typedef __bf16 bf16x8 __attribute__((ext_vector_type(8)));
typedef float f32x4 __attribute__((ext_vector_type(4)));

#define NBUCK 512      // bucket = col>>7; used 0..390 for N=50000
#define CH_MAX 4704    // max edges per sort-chunk block
#define PREP_BLKS 152  // 38912 weight elements / 256
#define DH 64          // deg-hist blocks in L2
#define CAP 2560       // per-bucket LDS edge capacity (mean 1534, +26 sigma)

__device__ __forceinline__ ushort f2b(float f) {  // fp32 -> bf16 RNE
  uint u = __float_as_uint(f);
  return (ushort)((u + 0x7FFFu + ((u >> 16) & 1u)) >> 16);
}
__device__ __forceinline__ float b2f_lo(uint u) { return __uint_as_float(u << 16); }
__device__ __forceinline__ float b2f_hi(uint u) { return __uint_as_float(u & 0xFFFF0000u); }

// ---------------- L1: weight prep || coarse chist || zero deg --------------
__global__ __launch_bounds__(256) void k_prep_chist_zero(const float* __restrict__ Wi,
                                                         const float* __restrict__ Wg,
                                                         const float* __restrict__ Wc,
                                                         ushort* __restrict__ Ti,
                                                         ushort* __restrict__ Tg,
                                                         ushort* __restrict__ Tc,
                                                         const int* __restrict__ col,
                                                         int* __restrict__ H2,
                                                         int* __restrict__ deg,
                                                         int E, int chunk, int sortb,
                                                         int n) {
  __shared__ int hist[NBUCK];
  const int tid = threadIdx.x;
  if (blockIdx.x < PREP_BLKS) {
    int idx = blockIdx.x * 256 + tid;
    if (idx < 16384) {
      int c = idx >> 7, k = idx & 127;
      Ti[c * 128 + k] = f2b(Wi[k * 128 + c]);
    } else if (idx < 32768) {
      int j = idx - 16384;
      int c = j >> 7, k = j & 127;
      Tg[c * 128 + k] = f2b(Wg[k * 128 + c]);
    } else if (idx < 38912) {
      int j = idx - 32768;
      int c = j >> 7, k = j & 127;
      Tc[c * 128 + k] = (c < 40) ? f2b(Wc[k * 40 + c]) : (ushort)0;
    }
    return;
  }
  if (blockIdx.x < PREP_BLKS + sortb) {
    const int blk = blockIdx.x - PREP_BLKS;
    for (int b = tid; b < NBUCK; b += 256) hist[b] = 0;
    __syncthreads();
    const int e0 = blk * chunk;
    const int cnt = min(chunk, E - e0);
    for (int i = tid; i < cnt; i += 256)
      atomicAdd(&hist[((unsigned)col[e0 + i]) >> 7], 1);
    __syncthreads();
    for (int b = tid; b < NBUCK; b += 256)
      H2[b * sortb + blk] = hist[b];
    return;
  }
  // zero deg
  const int zb = blockIdx.x - PREP_BLKS - sortb;
  const int i0 = zb * 1024 + tid * 4;
  if (i0 + 3 < n) *(int4*)&deg[i0] = make_int4(0, 0, 0, 0);
  else {
    if (i0 < n) deg[i0] = 0;
    if (i0 + 1 < n) deg[i0 + 1] = 0;
    if (i0 + 2 < n) deg[i0 + 2] = 0;
  }
}

// ---------------- L2: block0 scan || deg-hist || GEMM1 ---------------------
__global__ __launch_bounds__(512) void k_scan_hist_gemm1(const int* __restrict__ H2,
                                                         int* __restrict__ Hs,
                                                         int* __restrict__ cursor,
                                                         int sortb,
                                                         const int* __restrict__ col,
                                                         int* __restrict__ deg,
                                                         int E,
                                                         const float* __restrict__ x,
                                                         const ushort* __restrict__ Wti,
                                                         const float* __restrict__ b_in,
                                                         ushort* __restrict__ h,
                                                         int nrows, int n) {
  __shared__ __align__(16) char smem[69632];
  const int tid = threadIdx.x;
  if (blockIdx.x == 0) {
    int* sd = (int*)smem;  // 512 ints
    int s = 0;
    const int4* p = (const int4*)&H2[tid * sortb];
    for (int j = 0; j < sortb / 4; ++j) { int4 v = p[j]; s += v.x + v.y + v.z + v.w; }
    sd[tid] = s;
    __syncthreads();
    for (int off = 1; off < 512; off <<= 1) {
      int u = (tid >= off) ? sd[tid - off] : 0;
      __syncthreads();
      sd[tid] += u;
      __syncthreads();
    }
    Hs[tid] = sd[tid] - s;          // exclusive
    if (tid == 511) Hs[NBUCK] = sd[511];
    cursor[tid] = 0;
    return;
  }
  if (blockIdx.x <= DH) {
    const int hb = blockIdx.x - 1;
    for (int i = hb * 512 + tid; i < E; i += DH * 512) {
      int c = col[i];
      if ((unsigned)c < (unsigned)n) atomicAdd(&deg[c], 1);
    }
    return;
  }
  // GEMM1: h = relu(x @ W_in + b_in), 128-row tiles, 8 waves
  ushort (*As)[136] = (ushort(*)[136])smem;                    // 128 rows
  ushort (*Bs)[136] = (ushort(*)[136])(smem + 128 * 136 * 2);  // 128 rows
  const int row0 = (blockIdx.x - 1 - DH) * 128;
#pragma unroll
  for (int q = 0; q < 4; ++q) {
    int f = tid + 512 * q;
    int r = f >> 4, cw = f & 15;
    *(uint4*)&Bs[r][cw * 8] = *(const uint4*)&Wti[r * 128 + cw * 8];
  }
#pragma unroll
  for (int q = 0; q < 8; ++q) {
    int f = tid + 512 * q;
    int r = f >> 5, kc = f & 31;
    float4 v = make_float4(0.f, 0.f, 0.f, 0.f);
    if (row0 + r < nrows) v = *(const float4*)&x[(size_t)(row0 + r) * 128 + kc * 4];
    ushort4 o;
    o.x = f2b(v.x); o.y = f2b(v.y); o.z = f2b(v.z); o.w = f2b(v.w);
    *(ushort4*)&As[r][kc * 4] = o;
  }
  __syncthreads();

  const int wid = tid >> 6, lane = tid & 63;
  const int fr = lane & 15, fg = lane >> 4;
  f32x4 acc[8];
#pragma unroll
  for (int nn = 0; nn < 8; ++nn) acc[nn] = (f32x4){0.f, 0.f, 0.f, 0.f};
#pragma unroll
  for (int ks = 0; ks < 4; ++ks) {
    const int kb = ks * 32 + fg * 8;
    bf16x8 a = *(const bf16x8*)&As[wid * 16 + fr][kb];
#pragma unroll
    for (int nn = 0; nn < 8; ++nn) {
      bf16x8 b = *(const bf16x8*)&Bs[nn * 16 + fr][kb];
      acc[nn] = __builtin_amdgcn_mfma_f32_16x16x32_bf16(a, b, acc[nn], 0, 0, 0);
    }
  }
  const int r0 = row0 + wid * 16 + fg * 4;
#pragma unroll
  for (int nn = 0; nn < 8; ++nn) {
    const int cn = nn * 16 + fr;
    const float bv = b_in[cn];
#pragma unroll
    for (int i = 0; i < 4; ++i) {
      const int rr = r0 + i;
      if (rr < nrows) h[(size_t)rr * 128 + cn] = f2b(fmaxf(acc[nn][i] + bv, 0.f));
    }
  }
}

// ---------------- L3: reorder || GEMM2 (xws = dinv[r]*(h@W_gcn)) -----------
// ebuf record: (c_local<<16) | row  (row < 65536 since N=50000).
__global__ __launch_bounds__(256) void k_reorder_gemm2(const int* __restrict__ row,
                                                       const int* __restrict__ col,
                                                       const int* __restrict__ Hs,
                                                       int* __restrict__ cursor,
                                                       uint* __restrict__ ebuf,
                                                       int E, int chunk, int sortb,
                                                       const ushort* __restrict__ h,
                                                       const ushort* __restrict__ Wtg,
                                                       const int* __restrict__ deg,
                                                       ushort* __restrict__ xws,
                                                       int nrows) {
  __shared__ __align__(16) char smem[52224];
  const int tid = threadIdx.x;
  if (blockIdx.x < sortb) {
    int* hist   = (int*)smem;              // NBUCK
    int* lstart = hist + NBUCK;            // NBUCK
    int* cnt2   = lstart + NBUCK;          // NBUCK
    int* obase  = cnt2 + NBUCK;            // NBUCK
    uint* data  = (uint*)(obase + NBUCK);  // CH_MAX
    int* gpos   = (int*)(data + CH_MAX);   // CH_MAX
    int* sd     = gpos + CH_MAX;           // 256
    for (int b = tid; b < NBUCK; b += 256) { hist[b] = 0; cnt2[b] = 0; }
    __syncthreads();
    const int e0 = blockIdx.x * chunk;
    const int cnt = min(chunk, E - e0);
    for (int i = tid; i < cnt; i += 256)
      atomicAdd(&hist[((unsigned)col[e0 + i]) >> 7], 1);
    __syncthreads();
    const int h0 = hist[2 * tid], h1 = hist[2 * tid + 1];
    const int ps = h0 + h1;
    sd[tid] = ps;
    __syncthreads();
    for (int off = 1; off < 256; off <<= 1) {
      int u = (tid >= off) ? sd[tid - off] : 0;
      __syncthreads();
      sd[tid] += u;
      __syncthreads();
    }
    const int ex = sd[tid] - ps;
    lstart[2 * tid] = ex;
    lstart[2 * tid + 1] = ex + h0;
    obase[2 * tid]     = Hs[2 * tid]     + (h0 ? atomicAdd(&cursor[2 * tid], h0) : 0);
    obase[2 * tid + 1] = Hs[2 * tid + 1] + (h1 ? atomicAdd(&cursor[2 * tid + 1], h1) : 0);
    __syncthreads();
    for (int i = tid; i < cnt; i += 256) {
      const int c = col[e0 + i], r = row[e0 + i];
      const int b = ((unsigned)c) >> 7;
      const int rk = atomicAdd(&cnt2[b], 1);
      const int slot = lstart[b] + rk;
      data[slot] = ((uint)(c & 127) << 16) | (uint)r;
      gpos[slot] = obase[b] + rk;
    }
    __syncthreads();
    for (int i = tid; i < cnt; i += 256)
      ebuf[gpos[i]] = data[i];
    return;
  }
  // GEMM2: 64-row tile, 4 waves; epilogue scales by dinv[r]=rsqrt(deg[r]+1)
  ushort (*As)[136] = (ushort(*)[136])smem;                   // 64 rows
  ushort (*Bs)[136] = (ushort(*)[136])(smem + 64 * 136 * 2);  // 128 rows
  const int row0 = (blockIdx.x - sortb) * 64;
#pragma unroll
  for (int q = 0; q < 8; ++q) {
    int f = tid + 256 * q;
    int r = f >> 4, cw = f & 15;
    *(uint4*)&Bs[r][cw * 8] = *(const uint4*)&Wtg[r * 128 + cw * 8];
  }
#pragma unroll
  for (int q = 0; q < 4; ++q) {
    int f = tid + 256 * q;
    int r = f >> 4, cw = f & 15;
    uint4 v = make_uint4(0u, 0u, 0u, 0u);
    if (row0 + r < nrows) v = *(const uint4*)&h[(size_t)(row0 + r) * 128 + cw * 8];
    *(uint4*)&As[r][cw * 8] = v;
  }
  __syncthreads();
  const int wid = tid >> 6, lane = tid & 63;
  const int fr = lane & 15, fg = lane >> 4;
  f32x4 acc[8];
#pragma unroll
  for (int nn = 0; nn < 8; ++nn) acc[nn] = (f32x4){0.f, 0.f, 0.f, 0.f};
#pragma unroll
  for (int ks = 0; ks < 4; ++ks) {
    const int kb = ks * 32 + fg * 8;
    bf16x8 a = *(const bf16x8*)&As[wid * 16 + fr][kb];
#pragma unroll
    for (int nn = 0; nn < 8; ++nn) {
      bf16x8 b = *(const bf16x8*)&Bs[nn * 16 + fr][kb];
      acc[nn] = __builtin_amdgcn_mfma_f32_16x16x32_bf16(a, b, acc[nn], 0, 0, 0);
    }
  }
  const int r0 = row0 + wid * 16 + fg * 4;
  float dv[4];
#pragma unroll
  for (int i = 0; i < 4; ++i)
    dv[i] = (r0 + i < nrows) ? rsqrtf((float)deg[r0 + i] + 1.0f) : 0.f;
#pragma unroll
  for (int nn = 0; nn < 8; ++nn) {
    const int cn = nn * 16 + fr;
#pragma unroll
    for (int i = 0; i < 4; ++i) {
      const int rr = r0 + i;
      if (rr < nrows) xws[(size_t)rr * 128 + cn] = f2b(acc[nn][i] * dv[i]);
    }
  }
}

// ---------------- L4: per-bucket LDS sort + aggregate + classifier ---------
// One 512-thread block per 128-node bucket. ebuf window sorted in LDS (no
// global CSR). t rows in LDS, then 24 MFMA tiles (128x128x48) -> out.
__global__ __launch_bounds__(512) void k_sortaggout(const uint* __restrict__ ebuf,
                                                    const int* __restrict__ Hs,
                                                    const int* __restrict__ deg,
                                                    const ushort* __restrict__ xws,
                                                    const float* __restrict__ b_gcn,
                                                    const ushort* __restrict__ Wtc,
                                                    const float* __restrict__ bc,
                                                    float* __restrict__ out, int n) {
  __shared__ __align__(16) char smem[65408];
  ushort (*ts)[136] = (ushort(*)[136])smem;                 // 128x136
  ushort (*Bs)[136] = (ushort(*)[136])(smem + 34816);       // 48x136
  uint*   data   = (uint*)(smem + 47872);                   // CAP
  ushort* srt    = (ushort*)(smem + 58112);                 // CAP
  int*    cnt    = (int*)(smem + 63232);                    // 128
  int*    lstart = (int*)(smem + 63744);                    // 128
  int*    cnt2   = (int*)(smem + 64256);                    // 128
  int*    sd     = (int*)(smem + 64768);                    // 128
  __shared__ int nextn;
  const int tid = threadIdx.x;
  const int b = blockIdx.x;
  const int start = Hs[b];
  const int end = Hs[b + 1];
  const int len = end - start;
  const int wid = tid >> 6, lane = tid & 63;
  const int row0 = b * 128;
  const size_t off2 = (size_t)lane * 2;

  // stage W_cls tile: 768 uint4 chunks
#pragma unroll
  for (int q = 0; q < 2; ++q) {
    int f = tid + 512 * q;
    if (f < 768) {
      int r = f >> 4, cw = f & 15;
      *(uint4*)&Bs[r][cw * 8] = *(const uint4*)&Wtc[r * 128 + cw * 8];
    }
  }
  if (tid < 128) { cnt[tid] = 0; cnt2[tid] = 0; }
  if (tid == 0) nextn = 0;
  __syncthreads();

  const float2 bg = *(const float2*)&b_gcn[lane * 2];

  if (len <= CAP) {
    // load window + histogram
    for (int i = tid; i < len; i += 512) {
      uint v = ebuf[start + i];
      data[i] = v;
      atomicAdd(&cnt[v >> 16], 1);
    }
    __syncthreads();
    // exclusive scan of cnt[0..127]
    int cv = (tid < 128) ? cnt[tid] : 0;
    if (tid < 128) sd[tid] = cv;
    __syncthreads();
    for (int off = 1; off < 128; off <<= 1) {
      int u = (tid >= off && tid < 128) ? sd[tid - off] : 0;
      __syncthreads();
      if (tid < 128) sd[tid] += u;
      __syncthreads();
    }
    if (tid < 128) lstart[tid] = sd[tid] - cv;
    __syncthreads();
    // scatter rows into srt (segment-sorted)
    for (int i = tid; i < len; i += 512) {
      const uint v = data[i];
      const int c = v >> 16;
      const int rk = atomicAdd(&cnt2[c], 1);
      srt[lstart[c] + rk] = (ushort)(v & 0xFFFFu);
    }
    __syncthreads();
    // gather: dynamic node queue, wave per node
    for (;;) {
      int idx;
      if (lane == 0) idx = atomicAdd(&nextn, 1);
      idx = __shfl(idx, 0);
      if (idx >= 128) break;
      const int c = row0 + idx;
      ushort2 o = make_ushort2(0, 0);
      if (c < n) {
        const int s0 = lstart[idx];
        const int e0 = s0 + cnt[idx];
        const float dc = rsqrtf((float)deg[c] + 1.0f);
        uint sv = *(const uint*)&xws[(size_t)c * 128 + off2];  // self (pre-scaled)
        float ax = b2f_lo(sv), ay = b2f_hi(sv);
        int e = s0;
        for (; e + 4 <= e0; e += 4) {
          int r0 = srt[e], r1 = srt[e + 1], r2 = srt[e + 2], r3 = srt[e + 3];
          uint v0 = *(const uint*)&xws[(size_t)r0 * 128 + off2];
          uint v1 = *(const uint*)&xws[(size_t)r1 * 128 + off2];
          uint v2 = *(const uint*)&xws[(size_t)r2 * 128 + off2];
          uint v3 = *(const uint*)&xws[(size_t)r3 * 128 + off2];
          ax += (b2f_lo(v0) + b2f_lo(v1)) + (b2f_lo(v2) + b2f_lo(v3));
          ay += (b2f_hi(v0) + b2f_hi(v1)) + (b2f_hi(v2) + b2f_hi(v3));
        }
        for (; e < e0; ++e) {
          uint v = *(const uint*)&xws[(size_t)srt[e] * 128 + off2];
          ax += b2f_lo(v);
          ay += b2f_hi(v);
        }
        o.x = f2b(fmaxf(fmaf(dc, ax, bg.x), 0.f));
        o.y = f2b(fmaxf(fmaf(dc, ay, bg.y), 0.f));
      }
      *(ushort2*)&ts[idx][off2] = o;
    }
  } else {
    // fallback (never expected): per-node scan of the global window
    for (;;) {
      int idx;
      if (lane == 0) idx = atomicAdd(&nextn, 1);
      idx = __shfl(idx, 0);
      if (idx >= 128) break;
      const int c = row0 + idx;
      ushort2 o = make_ushort2(0, 0);
      if (c < n) {
        const float dc = rsqrtf((float)deg[c] + 1.0f);
        uint sv = *(const uint*)&xws[(size_t)c * 128 + off2];
        float ax = b2f_lo(sv), ay = b2f_hi(sv);
        for (int e = start; e < end; ++e) {
          const uint v = ebuf[e];
          if ((int)(v >> 16) == idx) {
            uint u = *(const uint*)&xws[(size_t)(v & 0xFFFFu) * 128 + off2];
            ax += b2f_lo(u);
            ay += b2f_hi(u);
          }
        }
        o.x = f2b(fmaxf(fmaf(dc, ax, bg.x), 0.f));
        o.y = f2b(fmaxf(fmaf(dc, ay, bg.y), 0.f));
      }
      *(ushort2*)&ts[idx][off2] = o;
    }
  }
  __syncthreads();

  // out = ts @ Wtc^T + bc : 8 row-blocks x 3 col-blocks = 24 tiles, 3/wave
  const int fr = lane & 15, fg = lane >> 4;
#pragma unroll
  for (int t3 = 0; t3 < 3; ++t3) {
    const int tile = wid + t3 * 8;
    const int rb = tile & 7, nb = tile >> 3;
    f32x4 acc = (f32x4){0.f, 0.f, 0.f, 0.f};
#pragma unroll
    for (int ks = 0; ks < 4; ++ks) {
      const int kb = ks * 32 + fg * 8;
      bf16x8 a = *(const bf16x8*)&ts[rb * 16 + fr][kb];
      bf16x8 bb = *(const bf16x8*)&Bs[nb * 16 + fr][kb];
      acc = __builtin_amdgcn_mfma_f32_16x16x32_bf16(a, bb, acc, 0, 0, 0);
    }
    const int cn = nb * 16 + fr;
    if (cn < 40) {
      const float bv = bc[cn];
      const int r0 = row0 + rb * 16 + fg * 4;
#pragma unroll
      for (int i = 0; i < 4; ++i) {
        const int rr = r0 + i;
        if (rr < n) out[(size_t)rr * 40 + cn] = acc[i] + bv;
      }
    }
  }
}

extern "C" void kernel_launch(void* const* d_in, const int* in_sizes, int n_in,
                              void* d_out, int out_size, void* d_ws, size_t ws_size,
                              hipStream_t stream) {
  const float* x     = (const float*)d_in[0];
  const int*   ei    = (const int*)d_in[1];
  const float* W_in  = (const float*)d_in[2];
  const float* b_in  = (const float*)d_in[3];
  const float* W_gcn = (const float*)d_in[4];
  const float* b_gcn = (const float*)d_in[5];
  const float* W_cls = (const float*)d_in[6];
  const float* b_cls = (const float*)d_in[7];
  float* out = (float*)d_out;

  const int N = in_sizes[0] / 128;
  const int E = in_sizes[1] / 2;
  const int* row = ei;
  const int* col = ei + E;

  const int sortb = (E + CH_MAX - 1) / CH_MAX;   // 128 for E=600000
  const int chunk = (E + sortb - 1) / sortb;      // <= CH_MAX
  const int nbuck = (N + 127) >> 7;               // 391
  const int zb    = (N + 1023) / 1024;            // deg-zero blocks

  // d_ws layout (~28.5 MB)
  ushort* h      = (ushort*)d_ws;                 // N*128 bf16
  ushort* xws    = h + (size_t)N * 128;           // N*128 bf16
  ushort* Wti    = xws + (size_t)N * 128;         // 128x128
  ushort* Wtg    = Wti + 128 * 128;               // 128x128
  ushort* Wtc    = Wtg + 128 * 128;               // 48x128 zero-padded
  uint*   ebuf   = (uint*)(Wtc + 48 * 128);       // E
  int*    H2     = (int*)(ebuf + E);              // NBUCK*sortb
  int*    Hs     = H2 + NBUCK * sortb;            // NBUCK+1
  int*    cursor = Hs + NBUCK + 1;                // NBUCK
  int*    deg    = cursor + NBUCK;                // N

  // L1: weight prep || coarse chist || zero deg
  k_prep_chist_zero<<<PREP_BLKS + sortb + zb, 256, 0, stream>>>(
      W_in, W_gcn, W_cls, Wti, Wtg, Wtc, col, H2, deg, E, chunk, sortb, N);

  // L2: bucket scan || deg histogram || GEMM1 (h = relu(x@W_in+b_in))
  k_scan_hist_gemm1<<<1 + DH + (N + 127) / 128, 512, 0, stream>>>(
      H2, Hs, cursor, sortb, col, deg, E, x, Wti, b_in, h, N, N);

  // L3: reorder || GEMM2 (xws = dinv[r]*(h@W_gcn))
  k_reorder_gemm2<<<sortb + (N + 63) / 64, 256, 0, stream>>>(
      row, col, Hs, cursor, ebuf, E, chunk, sortb, h, Wtg, deg, xws, N);

  // L4: per-bucket LDS sort + aggregate + classifier
  k_sortaggout<<<nbuck, 512, 0, stream>>>(ebuf, Hs, deg, xws, b_gcn,
                                          Wtc, b_cls, out, N);
}

// Round 11
// 107.892 us; speedup vs baseline: 1.0203x; 1.0203x over previous
//
#include <hip/hip_runtime.h>

// ---------------------------------------------------------------------------
// PYG_GCN: y = relu(x@W_in+b_in) -> GCNConv(W_gcn,b_gcn) -> relu -> @W_cls+b_cls
// N=50000, E=600000, D=128, C=40.
// R11: R9 pipeline + R10's deg/dinv-in-epilogue + quarter-wave uint4 gather.
//   L1 prep||chist||zero-deg -> L2 scan||deg-hist||GEMM1
//   -> L3 reorder||GEMM2(dinv epilogue) -> L4 fine sort -> L5 agg+out
// ---------------------------------------------------------------------------

typedef __bf16 bf16x8 __attribute__((ext_vector_type(8)));
typedef float f32x4 __attribute__((ext_vector_type(4)));

#define NBUCK 512      // bucket = col>>7; used 0..390 for N=50000
#define CH_MAX 4704    // max edges per sort-chunk block
#define PREP_BLKS 152  // 38912 weight elements / 256
#define DH 64          // deg-hist blocks in L2

__device__ __forceinline__ ushort f2b(float f) {  // fp32 -> bf16 RNE
  uint u = __float_as_uint(f);
  return (ushort)((u + 0x7FFFu + ((u >> 16) & 1u)) >> 16);
}
__device__ __forceinline__ float b2f_lo(uint u) { return __uint_as_float(u << 16); }
__device__ __forceinline__ float b2f_hi(uint u) { return __uint_as_float(u & 0xFFFF0000u); }

__device__ __forceinline__ void acc8(float* a, uint4 v) {
  a[0] += b2f_lo(v.x); a[1] += b2f_hi(v.x);
  a[2] += b2f_lo(v.y); a[3] += b2f_hi(v.y);
  a[4] += b2f_lo(v.z); a[5] += b2f_hi(v.z);
  a[6] += b2f_lo(v.w); a[7] += b2f_hi(v.w);
}

// ---------------- L1: weight prep || coarse chist || zero deg --------------
__global__ __launch_bounds__(256) void k_prep_chist_zero(const float* __restrict__ Wi,
                                                         const float* __restrict__ Wg,
                                                         const float* __restrict__ Wc,
                                                         ushort* __restrict__ Ti,
                                                         ushort* __restrict__ Tg,
                                                         ushort* __restrict__ Tc,
                                                         const int* __restrict__ col,
                                                         int* __restrict__ H2,
                                                         int* __restrict__ deg,
                                                         int E, int chunk, int sortb,
                                                         int n) {
  __shared__ int hist[NBUCK];
  const int tid = threadIdx.x;
  if (blockIdx.x < PREP_BLKS) {
    int idx = blockIdx.x * 256 + tid;
    if (idx < 16384) {
      int c = idx >> 7, k = idx & 127;
      Ti[c * 128 + k] = f2b(Wi[k * 128 + c]);
    } else if (idx < 32768) {
      int j = idx - 16384;
      int c = j >> 7, k = j & 127;
      Tg[c * 128 + k] = f2b(Wg[k * 128 + c]);
    } else if (idx < 38912) {
      int j = idx - 32768;
      int c = j >> 7, k = j & 127;
      Tc[c * 128 + k] = (c < 40) ? f2b(Wc[k * 40 + c]) : (ushort)0;
    }
    return;
  }
  if (blockIdx.x < PREP_BLKS + sortb) {
    const int blk = blockIdx.x - PREP_BLKS;
    for (int b = tid; b < NBUCK; b += 256) hist[b] = 0;
    __syncthreads();
    const int e0 = blk * chunk;
    const int cnt = min(chunk, E - e0);
    for (int i = tid; i < cnt; i += 256)
      atomicAdd(&hist[((unsigned)col[e0 + i]) >> 7], 1);
    __syncthreads();
    for (int b = tid; b < NBUCK; b += 256)
      H2[b * sortb + blk] = hist[b];
    return;
  }
  // zero deg
  const int zb = blockIdx.x - PREP_BLKS - sortb;
  const int i0 = zb * 1024 + tid * 4;
  if (i0 + 3 < n) *(int4*)&deg[i0] = make_int4(0, 0, 0, 0);
  else {
    if (i0 < n) deg[i0] = 0;
    if (i0 + 1 < n) deg[i0 + 1] = 0;
    if (i0 + 2 < n) deg[i0 + 2] = 0;
  }
}

// ---------------- L2: block0 scan || deg-hist || GEMM1 ---------------------
__global__ __launch_bounds__(512) void k_scan_hist_gemm1(const int* __restrict__ H2,
                                                         int* __restrict__ Hs,
                                                         int* __restrict__ cursor,
                                                         int sortb,
                                                         const int* __restrict__ col,
                                                         int* __restrict__ deg,
                                                         int E,
                                                         const float* __restrict__ x,
                                                         const ushort* __restrict__ Wti,
                                                         const float* __restrict__ b_in,
                                                         ushort* __restrict__ h,
                                                         int nrows, int n) {
  __shared__ __align__(16) char smem[69632];
  const int tid = threadIdx.x;
  if (blockIdx.x == 0) {
    int* sd = (int*)smem;  // 512 ints
    int s = 0;
    const int4* p = (const int4*)&H2[tid * sortb];
    for (int j = 0; j < sortb / 4; ++j) { int4 v = p[j]; s += v.x + v.y + v.z + v.w; }
    sd[tid] = s;
    __syncthreads();
    for (int off = 1; off < 512; off <<= 1) {
      int u = (tid >= off) ? sd[tid - off] : 0;
      __syncthreads();
      sd[tid] += u;
      __syncthreads();
    }
    Hs[tid] = sd[tid] - s;          // exclusive
    if (tid == 511) Hs[NBUCK] = sd[511];
    cursor[tid] = 0;
    return;
  }
  if (blockIdx.x <= DH) {
    const int hb = blockIdx.x - 1;
    for (int i = hb * 512 + tid; i < E; i += DH * 512) {
      int c = col[i];
      if ((unsigned)c < (unsigned)n) atomicAdd(&deg[c], 1);
    }
    return;
  }
  // GEMM1: h = relu(x @ W_in + b_in), 128-row tiles, 8 waves
  ushort (*As)[136] = (ushort(*)[136])smem;                    // 128 rows
  ushort (*Bs)[136] = (ushort(*)[136])(smem + 128 * 136 * 2);  // 128 rows
  const int row0 = (blockIdx.x - 1 - DH) * 128;
#pragma unroll
  for (int q = 0; q < 4; ++q) {
    int f = tid + 512 * q;
    int r = f >> 4, cw = f & 15;
    *(uint4*)&Bs[r][cw * 8] = *(const uint4*)&Wti[r * 128 + cw * 8];
  }
#pragma unroll
  for (int q = 0; q < 8; ++q) {
    int f = tid + 512 * q;
    int r = f >> 5, kc = f & 31;
    float4 v = make_float4(0.f, 0.f, 0.f, 0.f);
    if (row0 + r < nrows) v = *(const float4*)&x[(size_t)(row0 + r) * 128 + kc * 4];
    ushort4 o;
    o.x = f2b(v.x); o.y = f2b(v.y); o.z = f2b(v.z); o.w = f2b(v.w);
    *(ushort4*)&As[r][kc * 4] = o;
  }
  __syncthreads();

  const int wid = tid >> 6, lane = tid & 63;
  const int fr = lane & 15, fg = lane >> 4;
  f32x4 acc[8];
#pragma unroll
  for (int nn = 0; nn < 8; ++nn) acc[nn] = (f32x4){0.f, 0.f, 0.f, 0.f};
#pragma unroll
  for (int ks = 0; ks < 4; ++ks) {
    const int kb = ks * 32 + fg * 8;
    bf16x8 a = *(const bf16x8*)&As[wid * 16 + fr][kb];
#pragma unroll
    for (int nn = 0; nn < 8; ++nn) {
      bf16x8 b = *(const bf16x8*)&Bs[nn * 16 + fr][kb];
      acc[nn] = __builtin_amdgcn_mfma_f32_16x16x32_bf16(a, b, acc[nn], 0, 0, 0);
    }
  }
  const int r0 = row0 + wid * 16 + fg * 4;
#pragma unroll
  for (int nn = 0; nn < 8; ++nn) {
    const int cn = nn * 16 + fr;
    const float bv = b_in[cn];
#pragma unroll
    for (int i = 0; i < 4; ++i) {
      const int rr = r0 + i;
      if (rr < nrows) h[(size_t)rr * 128 + cn] = f2b(fmaxf(acc[nn][i] + bv, 0.f));
    }
  }
}

// ---------------- L3: reorder || GEMM2 (xws = dinv[r]*(h@W_gcn)) -----------
// ebuf record: (c_local<<16) | row  (row < 65536 since N=50000).
__global__ __launch_bounds__(256) void k_reorder_gemm2(const int* __restrict__ row,
                                                       const int* __restrict__ col,
                                                       const int* __restrict__ Hs,
                                                       int* __restrict__ cursor,
                                                       uint* __restrict__ ebuf,
                                                       int E, int chunk, int sortb,
                                                       const ushort* __restrict__ h,
                                                       const ushort* __restrict__ Wtg,
                                                       const int* __restrict__ deg,
                                                       ushort* __restrict__ xws,
                                                       int nrows) {
  __shared__ __align__(16) char smem[52224];
  const int tid = threadIdx.x;
  if (blockIdx.x < sortb) {
    int* hist   = (int*)smem;              // NBUCK
    int* lstart = hist + NBUCK;            // NBUCK
    int* cnt2   = lstart + NBUCK;          // NBUCK
    int* obase  = cnt2 + NBUCK;            // NBUCK
    uint* data  = (uint*)(obase + NBUCK);  // CH_MAX
    int* gpos   = (int*)(data + CH_MAX);   // CH_MAX
    int* sd     = gpos + CH_MAX;           // 256
    for (int b = tid; b < NBUCK; b += 256) { hist[b] = 0; cnt2[b] = 0; }
    __syncthreads();
    const int e0 = blockIdx.x * chunk;
    const int cnt = min(chunk, E - e0);
    for (int i = tid; i < cnt; i += 256)
      atomicAdd(&hist[((unsigned)col[e0 + i]) >> 7], 1);
    __syncthreads();
    const int h0 = hist[2 * tid], h1 = hist[2 * tid + 1];
    const int ps = h0 + h1;
    sd[tid] = ps;
    __syncthreads();
    for (int off = 1; off < 256; off <<= 1) {
      int u = (tid >= off) ? sd[tid - off] : 0;
      __syncthreads();
      sd[tid] += u;
      __syncthreads();
    }
    const int ex = sd[tid] - ps;
    lstart[2 * tid] = ex;
    lstart[2 * tid + 1] = ex + h0;
    obase[2 * tid]     = Hs[2 * tid]     + (h0 ? atomicAdd(&cursor[2 * tid], h0) : 0);
    obase[2 * tid + 1] = Hs[2 * tid + 1] + (h1 ? atomicAdd(&cursor[2 * tid + 1], h1) : 0);
    __syncthreads();
    for (int i = tid; i < cnt; i += 256) {
      const int c = col[e0 + i], r = row[e0 + i];
      const int b = ((unsigned)c) >> 7;
      const int rk = atomicAdd(&cnt2[b], 1);
      const int slot = lstart[b] + rk;
      data[slot] = ((uint)(c & 127) << 16) | (uint)r;
      gpos[slot] = obase[b] + rk;
    }
    __syncthreads();
    for (int i = tid; i < cnt; i += 256)
      ebuf[gpos[i]] = data[i];
    return;
  }
  // GEMM2: 64-row tile, 4 waves; epilogue scales by dinv[r]=rsqrt(deg[r]+1)
  ushort (*As)[136] = (ushort(*)[136])smem;                   // 64 rows
  ushort (*Bs)[136] = (ushort(*)[136])(smem + 64 * 136 * 2);  // 128 rows
  const int row0 = (blockIdx.x - sortb) * 64;
#pragma unroll
  for (int q = 0; q < 8; ++q) {
    int f = tid + 256 * q;
    int r = f >> 4, cw = f & 15;
    *(uint4*)&Bs[r][cw * 8] = *(const uint4*)&Wtg[r * 128 + cw * 8];
  }
#pragma unroll
  for (int q = 0; q < 4; ++q) {
    int f = tid + 256 * q;
    int r = f >> 4, cw = f & 15;
    uint4 v = make_uint4(0u, 0u, 0u, 0u);
    if (row0 + r < nrows) v = *(const uint4*)&h[(size_t)(row0 + r) * 128 + cw * 8];
    *(uint4*)&As[r][cw * 8] = v;
  }
  __syncthreads();
  const int wid = tid >> 6, lane = tid & 63;
  const int fr = lane & 15, fg = lane >> 4;
  f32x4 acc[8];
#pragma unroll
  for (int nn = 0; nn < 8; ++nn) acc[nn] = (f32x4){0.f, 0.f, 0.f, 0.f};
#pragma unroll
  for (int ks = 0; ks < 4; ++ks) {
    const int kb = ks * 32 + fg * 8;
    bf16x8 a = *(const bf16x8*)&As[wid * 16 + fr][kb];
#pragma unroll
    for (int nn = 0; nn < 8; ++nn) {
      bf16x8 b = *(const bf16x8*)&Bs[nn * 16 + fr][kb];
      acc[nn] = __builtin_amdgcn_mfma_f32_16x16x32_bf16(a, b, acc[nn], 0, 0, 0);
    }
  }
  const int r0 = row0 + wid * 16 + fg * 4;
  float dv[4];
#pragma unroll
  for (int i = 0; i < 4; ++i)
    dv[i] = (r0 + i < nrows) ? rsqrtf((float)deg[r0 + i] + 1.0f) : 0.f;
#pragma unroll
  for (int nn = 0; nn < 8; ++nn) {
    const int cn = nn * 16 + fr;
#pragma unroll
    for (int i = 0; i < 4; ++i) {
      const int rr = r0 + i;
      if (rr < nrows) xws[(size_t)rr * 128 + cn] = f2b(acc[nn][i] * dv[i]);
    }
  }
}

// ---------------- L4: per-bucket fine sort -> srcrow CSR + P ---------------
// P[node] = END offset of node's segment (seg = [P[c-1], P[c]), P[-1] := 0).
__global__ __launch_bounds__(256) void k_sort2(const uint* __restrict__ ebuf,
                                               const int* __restrict__ Hs,
                                               int* __restrict__ srcrow,
                                               int* __restrict__ P,
                                               int n) {
  __shared__ int cnt[128];
  __shared__ int lstart[128];
  __shared__ int cnt2[128];
  __shared__ int sd[256];
  const int tid = threadIdx.x;
  if (tid < 128) { cnt[tid] = 0; cnt2[tid] = 0; }
  __syncthreads();
  const int b = blockIdx.x;
  const int start = Hs[b];
  const int end = Hs[b + 1];
  for (int i = start + tid; i < end; i += 256)
    atomicAdd(&cnt[ebuf[i] >> 16], 1);
  __syncthreads();
  const int cv = (tid < 128) ? cnt[tid] : 0;
  sd[tid] = cv;
  __syncthreads();
  for (int off = 1; off < 256; off <<= 1) {
    int u = (tid >= off) ? sd[tid - off] : 0;
    __syncthreads();
    sd[tid] += u;
    __syncthreads();
  }
  if (tid < 128) {
    const int ex = sd[tid] - cv;
    lstart[tid] = ex;
    const int node = b * 128 + tid;
    if (node < n) P[node] = start + ex + cv;
  }
  __syncthreads();
  for (int i = start + tid; i < end; i += 256) {
    const uint v = ebuf[i];
    const int c = v >> 16;
    const int rk = atomicAdd(&cnt2[c], 1);
    srcrow[start + lstart[c] + rk] = (int)(v & 0xFFFFu);
  }
}

// ---------------- L5: fused aggregate + classifier -------------------------
// 512 threads / 32 nodes per block. Quarter-wave gather: each 16-lane quarter
// handles one edge via uint4 (16B/lane); 8 edges per wave-iteration.
// Cross-quarter reduce via shfl_xor(16/32). Then 6 waves do 32x128x48 MFMA.
__global__ __launch_bounds__(512) void k_aggout(const int* __restrict__ P,
                                                const int* __restrict__ srcrow,
                                                const ushort* __restrict__ xws,
                                                const int* __restrict__ deg,
                                                const float* __restrict__ b_gcn,
                                                const ushort* __restrict__ Wtc,
                                                const float* __restrict__ bc,
                                                float* __restrict__ out, int n) {
  __shared__ ushort ts[32][136];
  __shared__ ushort Bs[48][136];
  __shared__ int nextn;
  const int tid = threadIdx.x;
#pragma unroll
  for (int q = 0; q < 2; ++q) {
    int f = tid + 512 * q;
    if (f < 768) {
      int r = f >> 4, cw = f & 15;
      *(uint4*)&Bs[r][cw * 8] = *(const uint4*)&Wtc[r * 128 + cw * 8];
    }
  }
  if (tid == 0) nextn = 0;
  __syncthreads();

  const int wid = tid >> 6, lane = tid & 63;
  const int qt = lane >> 4, lq = lane & 15;   // quarter / lane-in-quarter
  const int row0 = blockIdx.x * 32;
  const size_t coff = (size_t)lq * 8;         // 8 cols per lane

  float bg[8];
#pragma unroll
  for (int j = 0; j < 8; ++j) bg[j] = b_gcn[lq * 8 + j];

  for (;;) {
    int idx;
    if (lane == 0) idx = atomicAdd(&nextn, 1);
    idx = __shfl(idx, 0);
    if (idx >= 32) break;
    const int c = row0 + idx;
    if (c < n) {
      const int begin = (c == 0) ? 0 : P[c - 1];
      const int end = P[c];
      float a[8];
#pragma unroll
      for (int j = 0; j < 8; ++j) a[j] = 0.f;
      int e = begin;
      for (; e + 8 <= end; e += 8) {   // 8 edges per iteration (2 per quarter)
        const int r0 = srcrow[e + qt];
        const int r1 = srcrow[e + 4 + qt];
        const uint4 v0 = *(const uint4*)&xws[(size_t)r0 * 128 + coff];
        const uint4 v1 = *(const uint4*)&xws[(size_t)r1 * 128 + coff];
        acc8(a, v0);
        acc8(a, v1);
      }
      for (; e < end; e += 4) {        // predicated tail, up to 4 edges/iter
        if (e + qt < end) {
          const int r = srcrow[e + qt];
          const uint4 v = *(const uint4*)&xws[(size_t)r * 128 + coff];
          acc8(a, v);
        }
      }
      // cross-quarter reduction: lanes lq, lq+16, lq+32, lq+48 -> total
#pragma unroll
      for (int j = 0; j < 8; ++j) {
        a[j] += __shfl_xor(a[j], 16);
        a[j] += __shfl_xor(a[j], 32);
      }
      if (qt == 0) {
        const uint4 sv = *(const uint4*)&xws[(size_t)c * 128 + coff];  // self
        const float dc = rsqrtf((float)deg[c] + 1.0f);
        const float t0 = fmaxf(fmaf(dc, a[0] + b2f_lo(sv.x), bg[0]), 0.f);
        const float t1 = fmaxf(fmaf(dc, a[1] + b2f_hi(sv.x), bg[1]), 0.f);
        const float t2 = fmaxf(fmaf(dc, a[2] + b2f_lo(sv.y), bg[2]), 0.f);
        const float t3 = fmaxf(fmaf(dc, a[3] + b2f_hi(sv.y), bg[3]), 0.f);
        const float t4 = fmaxf(fmaf(dc, a[4] + b2f_lo(sv.z), bg[4]), 0.f);
        const float t5 = fmaxf(fmaf(dc, a[5] + b2f_hi(sv.z), bg[5]), 0.f);
        const float t6 = fmaxf(fmaf(dc, a[6] + b2f_lo(sv.w), bg[6]), 0.f);
        const float t7 = fmaxf(fmaf(dc, a[7] + b2f_hi(sv.w), bg[7]), 0.f);
        uint4 o;
        o.x = ((uint)f2b(t1) << 16) | f2b(t0);
        o.y = ((uint)f2b(t3) << 16) | f2b(t2);
        o.z = ((uint)f2b(t5) << 16) | f2b(t4);
        o.w = ((uint)f2b(t7) << 16) | f2b(t6);
        *(uint4*)&ts[idx][coff] = o;
      }
    } else if (qt == 0) {
      *(uint4*)&ts[idx][coff] = make_uint4(0u, 0u, 0u, 0u);
    }
  }
  __syncthreads();

  // out = ts @ Wtc^T + bc : 2 row-blocks x 3 col-blocks = 6 MFMA tiles
  if (wid < 6) {
    const int rb = wid & 1, nb = wid >> 1;
    const int fr = lane & 15, fg = lane >> 4;
    f32x4 acc = (f32x4){0.f, 0.f, 0.f, 0.f};
#pragma unroll
    for (int ks = 0; ks < 4; ++ks) {
      const int kb = ks * 32 + fg * 8;
      bf16x8 aa = *(const bf16x8*)&ts[rb * 16 + fr][kb];
      bf16x8 bb = *(const bf16x8*)&Bs[nb * 16 + fr][kb];
      acc = __builtin_amdgcn_mfma_f32_16x16x32_bf16(aa, bb, acc, 0, 0, 0);
    }
    const int cn = nb * 16 + fr;
    if (cn < 40) {
      const float bv = bc[cn];
      const int r0 = row0 + rb * 16 + fg * 4;
#pragma unroll
      for (int i = 0; i < 4; ++i) {
        const int rr = r0 + i;
        if (rr < n) out[(size_t)rr * 40 + cn] = acc[i] + bv;
      }
    }
  }
}

extern "C" void kernel_launch(void* const* d_in, const int* in_sizes, int n_in,
                              void* d_out, int out_size, void* d_ws, size_t ws_size,
                              hipStream_t stream) {
  const float* x     = (const float*)d_in[0];
  const int*   ei    = (const int*)d_in[1];
  const float* W_in  = (const float*)d_in[2];
  const float* b_in  = (const float*)d_in[3];
  const float* W_gcn = (const float*)d_in[4];
  const float* b_gcn = (const float*)d_in[5];
  const float* W_cls = (const float*)d_in[6];
  const float* b_cls = (const float*)d_in[7];
  float* out = (float*)d_out;

  const int N = in_sizes[0] / 128;
  const int E = in_sizes[1] / 2;
  const int* row = ei;
  const int* col = ei + E;

  const int sortb = (E + CH_MAX - 1) / CH_MAX;   // 128 for E=600000
  const int chunk = (E + sortb - 1) / sortb;      // <= CH_MAX
  const int nbuck = (N + 127) >> 7;               // 391
  const int zb    = (N + 1023) / 1024;            // deg-zero blocks

  // d_ws layout (~31.3 MB)
  ushort* h      = (ushort*)d_ws;                 // N*128 bf16
  ushort* xws    = h + (size_t)N * 128;           // N*128 bf16
  ushort* Wti    = xws + (size_t)N * 128;         // 128x128
  ushort* Wtg    = Wti + 128 * 128;               // 128x128
  ushort* Wtc    = Wtg + 128 * 128;               // 48x128 zero-padded
  uint*   ebuf   = (uint*)(Wtc + 48 * 128);       // E
  int*    srcrow = (int*)(ebuf + E);              // E
  int*    H2     = srcrow + E;                    // NBUCK*sortb
  int*    Hs     = H2 + NBUCK * sortb;            // NBUCK+1
  int*    cursor = Hs + NBUCK + 1;                // NBUCK
  int*    deg    = cursor + NBUCK;                // N
  int*    P      = deg + N;                       // N

  // L1: weight prep || coarse chist || zero deg
  k_prep_chist_zero<<<PREP_BLKS + sortb + zb, 256, 0, stream>>>(
      W_in, W_gcn, W_cls, Wti, Wtg, Wtc, col, H2, deg, E, chunk, sortb, N);

  // L2: bucket scan || deg histogram || GEMM1 (h = relu(x@W_in+b_in))
  k_scan_hist_gemm1<<<1 + DH + (N + 127) / 128, 512, 0, stream>>>(
      H2, Hs, cursor, sortb, col, deg, E, x, Wti, b_in, h, N, N);

  // L3: reorder || GEMM2 (xws = dinv[r]*(h@W_gcn))
  k_reorder_gemm2<<<sortb + (N + 63) / 64, 256, 0, stream>>>(
      row, col, Hs, cursor, ebuf, E, chunk, sortb, h, Wtg, deg, xws, N);

  // L4: per-bucket fine sort -> srcrow CSR + P
  k_sort2<<<nbuck, 256, 0, stream>>>(ebuf, Hs, srcrow, P, N);

  // L5: out = relu(dinv[c]*(sum xws[r] + xws[c]) + b_gcn) @ W_cls + b_cls
  k_aggout<<<(N + 31) / 32, 512, 0, stream>>>(P, srcrow, xws, deg, b_gcn,
                                              Wtc, b_cls, out, N);
}